// Round 5
// baseline (817.381 us; speedup 1.0000x reference)
//
#include <hip/hip_runtime.h>
#include <hip/hip_bf16.h>
#include <math.h>

// Problem constants (B,S,D,H,R,N = 4,2048,1024,16,64,16)
#define Bq 4
#define Sq 2048
#define Dq 1024
#define Hq 16
#define Rq 64
#define Nq 16
#define DHq 64
#define Mq (Bq * Sq)   // 8192 tokens
#define NRq (Nq * Rq)  // 1024

static_assert(NRq == Dq, "layout assumption");

typedef __attribute__((ext_vector_type(8))) short short8v;  // 8 bf16 (4 VGPRs)
typedef __attribute__((ext_vector_type(4))) float f32x4;    // 4 fp32 acc

// ---------------------------------------------------------------------------
// bf16 split helpers: x ~= hi + lo with ~2^-17 relative error.
__device__ inline ushort bf16_rne(float x) {
    __hip_bfloat16 b = __float2bfloat16(x);
    return *reinterpret_cast<ushort*>(&b);
}
__device__ inline float bf16_to_f(ushort u) {
    union { unsigned int i; float f; } c;
    c.i = ((unsigned int)u) << 16;
    return c.f;
}
__device__ inline void split2(float x, ushort& h, ushort& l) {
    h = bf16_rne(x);
    l = bf16_rne(x - bf16_to_f(h));
}

// Generic elementwise split: in fp32[n] -> hi/lo bf16[n]. 4 elems/thread.
__global__ __launch_bounds__(256) void split_kernel(const float* __restrict__ in,
                                                    ushort* __restrict__ hi,
                                                    ushort* __restrict__ lo) {
    const int i = blockIdx.x * 256 + threadIdx.x;
    const float4 v = *reinterpret_cast<const float4*>(&in[(size_t)i * 4]);
    ushort4 h4, l4;
    split2(v.x, h4.x, l4.x);
    split2(v.y, h4.y, l4.y);
    split2(v.z, h4.z, l4.z);
    split2(v.w, h4.w, l4.w);
    *reinterpret_cast<ushort4*>(&hi[(size_t)i * 4]) = h4;
    *reinterpret_cast<ushort4*>(&lo[(size_t)i * 4]) = l4;
}

// C_all^T split: out[nr][d] = cn[n][d][r]  (cn: [N,D,R] fp32).
__global__ __launch_bounds__(256) void callT_split_kernel(const float* __restrict__ cn,
                                                          ushort* __restrict__ bhi,
                                                          ushort* __restrict__ blo) {
    const int idx = blockIdx.x * 256 + threadIdx.x;  // over 1M
    const int nr = idx >> 10, d = idx & 1023;
    const int n = nr >> 6, r = nr & 63;
    const float v = cn[((size_t)(n << 10) + d) * 64 + r];
    ushort h, l;
    split2(v, h, l);
    bhi[idx] = h;
    blo[idx] = l;
}

// Transpose+split 1024x1024: out[n][k] = in[k][n], fp32 -> hi/lo bf16. 64x64 tiles.
__global__ __launch_bounds__(256) void transpose_split_kernel(const float* __restrict__ in,
                                                              ushort* __restrict__ bhi,
                                                              ushort* __restrict__ blo) {
    __shared__ float tl[64][65];
    const int bx = blockIdx.x;        // 256 blocks = 16x16 tiles
    const int tn0 = (bx & 15) * 64;   // input col block
    const int tk0 = (bx >> 4) * 64;   // input row block
    const int r0 = threadIdx.x >> 4;  // 0..15
    const int c4 = (threadIdx.x & 15) * 4;
#pragma unroll
    for (int p = 0; p < 4; p++) {
        const int row = r0 + p * 16;
        const float4 v = *reinterpret_cast<const float4*>(&in[(size_t)(tk0 + row) * 1024 + tn0 + c4]);
        tl[row][c4 + 0] = v.x; tl[row][c4 + 1] = v.y;
        tl[row][c4 + 2] = v.z; tl[row][c4 + 3] = v.w;
    }
    __syncthreads();
#pragma unroll
    for (int p = 0; p < 4; p++) {
        const int orow = r0 + p * 16;  // output row (= input col)
        ushort4 h4, l4;
        split2(tl[c4 + 0][orow], h4.x, l4.x);
        split2(tl[c4 + 1][orow], h4.y, l4.y);
        split2(tl[c4 + 2][orow], h4.z, l4.z);
        split2(tl[c4 + 3][orow], h4.w, l4.w);
        const size_t o = (size_t)(tn0 + orow) * 1024 + tk0 + c4;
        *reinterpret_cast<ushort4*>(&bhi[o]) = h4;
        *reinterpret_cast<ushort4*>(&blo[o]) = l4;
    }
}

// V^T split: Vf fp32 [tok=b*2048+s][h*64+d] -> VT hi/lo bf16 [bh][d][s(2048)].
// grid (32 s-tiles, 64 bh), block 256; 64x64 tile through LDS.
__global__ __launch_bounds__(256) void vt_split_kernel(const float* __restrict__ Vf,
                                                       ushort* __restrict__ vthi,
                                                       ushort* __restrict__ vtlo) {
    __shared__ float tl[64][65];
    const int st = blockIdx.x, bh = blockIdx.y;
    const int b = bh >> 4, h = bh & 15;
    const int i = threadIdx.x >> 2;          // 0..63
    const int c16 = (threadIdx.x & 3) * 16;  // 0,16,32,48
#pragma unroll
    for (int p = 0; p < 4; p++) {
        const float4 v = *reinterpret_cast<const float4*>(
            &Vf[((size_t)(b * Sq + st * 64 + i)) * Dq + h * 64 + c16 + p * 4]);
        tl[i][c16 + p * 4 + 0] = v.x; tl[i][c16 + p * 4 + 1] = v.y;
        tl[i][c16 + p * 4 + 2] = v.z; tl[i][c16 + p * 4 + 3] = v.w;
    }
    __syncthreads();
    // write: d = i, keys c16..c16+15
    const size_t obase = ((size_t)(bh * 64 + i)) * Sq + st * 64 + c16;
#pragma unroll
    for (int p = 0; p < 4; p++) {
        ushort4 h4, l4;
        split2(tl[c16 + p * 4 + 0][i], h4.x, l4.x);
        split2(tl[c16 + p * 4 + 1][i], h4.y, l4.y);
        split2(tl[c16 + p * 4 + 2][i], h4.z, l4.z);
        split2(tl[c16 + p * 4 + 3][i], h4.w, l4.w);
        *reinterpret_cast<ushort4*>(&vthi[obase + p * 4]) = h4;
        *reinterpret_cast<ushort4*>(&vtlo[obase + p * 4]) = l4;
    }
}

// ---------------------------------------------------------------------------
// MFMA bf16x3 GEMM (audited, unchanged). C[M][N] fp32 = (Ahi+Alo)@(Bhi+Blo),
// B supplied TRANSPOSED ([N][K] row-major). 128x128 tile, BK=32, 4 waves.
#define LPITCH 40
__global__ __launch_bounds__(256) void gemm_bf16x3(const ushort* __restrict__ Ahi,
                                                   const ushort* __restrict__ Alo,
                                                   const ushort* __restrict__ Bthi,
                                                   const ushort* __restrict__ Btlo,
                                                   float* __restrict__ C,
                                                   int M, int N, int K) {
    __shared__ ushort lAhi[128 * LPITCH];
    __shared__ ushort lAlo[128 * LPITCH];
    __shared__ ushort lBhi[128 * LPITCH];
    __shared__ ushort lBlo[128 * LPITCH];
    const int tid = threadIdx.x;
    const int lane = tid & 63;
    const int wave = tid >> 6;
    const int wr = wave >> 1, wc = wave & 1;  // 2x2 wave grid
    const int row0 = blockIdx.y * 128, col0 = blockIdx.x * 128;

    const int srow = tid >> 2;       // 0..63 staging row
    const int spart = tid & 3;       // k-part: 8 bf16 = 16B
    const int lrow = lane & 15;      // frag row/col
    const int kgrp = lane >> 4;      // frag k-group

    f32x4 acc[4][4];
#pragma unroll
    for (int i = 0; i < 4; i++)
#pragma unroll
        for (int j = 0; j < 4; j++) acc[i][j] = (f32x4)(0.f);

    for (int k0 = 0; k0 < K; k0 += 32) {
        const size_t ga0 = (size_t)(row0 + srow) * K + k0 + spart * 8;
        const size_t ga1 = ga0 + (size_t)64 * K;
        const size_t gb0 = (size_t)(col0 + srow) * K + k0 + spart * 8;
        const size_t gb1 = gb0 + (size_t)64 * K;
        const short8v ah0 = *reinterpret_cast<const short8v*>(Ahi + ga0);
        const short8v ah1 = *reinterpret_cast<const short8v*>(Ahi + ga1);
        const short8v al0 = *reinterpret_cast<const short8v*>(Alo + ga0);
        const short8v al1 = *reinterpret_cast<const short8v*>(Alo + ga1);
        const short8v bh0 = *reinterpret_cast<const short8v*>(Bthi + gb0);
        const short8v bh1 = *reinterpret_cast<const short8v*>(Bthi + gb1);
        const short8v bl0 = *reinterpret_cast<const short8v*>(Btlo + gb0);
        const short8v bl1 = *reinterpret_cast<const short8v*>(Btlo + gb1);
        __syncthreads();
        const int s0 = srow * LPITCH + spart * 8;
        const int s1 = (srow + 64) * LPITCH + spart * 8;
        *reinterpret_cast<short8v*>(&lAhi[s0]) = ah0;
        *reinterpret_cast<short8v*>(&lAhi[s1]) = ah1;
        *reinterpret_cast<short8v*>(&lAlo[s0]) = al0;
        *reinterpret_cast<short8v*>(&lAlo[s1]) = al1;
        *reinterpret_cast<short8v*>(&lBhi[s0]) = bh0;
        *reinterpret_cast<short8v*>(&lBhi[s1]) = bh1;
        *reinterpret_cast<short8v*>(&lBlo[s0]) = bl0;
        *reinterpret_cast<short8v*>(&lBlo[s1]) = bl1;
        __syncthreads();
        short8v afh[4], afl[4], bfh[4], bfl[4];
#pragma unroll
        for (int im = 0; im < 4; im++) {
            const int a = (wr * 64 + im * 16 + lrow) * LPITCH + kgrp * 8;
            afh[im] = *reinterpret_cast<const short8v*>(&lAhi[a]);
            afl[im] = *reinterpret_cast<const short8v*>(&lAlo[a]);
        }
#pragma unroll
        for (int in = 0; in < 4; in++) {
            const int b = (wc * 64 + in * 16 + lrow) * LPITCH + kgrp * 8;
            bfh[in] = *reinterpret_cast<const short8v*>(&lBhi[b]);
            bfl[in] = *reinterpret_cast<const short8v*>(&lBlo[b]);
        }
#pragma unroll
        for (int im = 0; im < 4; im++)
#pragma unroll
            for (int in = 0; in < 4; in++) {
                acc[im][in] = __builtin_amdgcn_mfma_f32_16x16x32_bf16(afh[im], bfh[in], acc[im][in], 0, 0, 0);
                acc[im][in] = __builtin_amdgcn_mfma_f32_16x16x32_bf16(afh[im], bfl[in], acc[im][in], 0, 0, 0);
                acc[im][in] = __builtin_amdgcn_mfma_f32_16x16x32_bf16(afl[im], bfh[in], acc[im][in], 0, 0, 0);
            }
    }
#pragma unroll
    for (int im = 0; im < 4; im++) {
        const int orow = row0 + wr * 64 + im * 16 + kgrp * 4;
#pragma unroll
        for (int in = 0; in < 4; in++) {
            const int ocol = col0 + wc * 64 + in * 16 + lrow;
#pragma unroll
            for (int j = 0; j < 4; j++) C[(size_t)(orow + j) * N + ocol] = acc[im][in][j];
        }
    }
}

// ---------------------------------------------------------------------------
// h[t,r] = sum_n cw[t,n]*T[t,n*64+r];  Gq[t,n*64+r] = ewq[t,n]*h;  Gv in-place over T.
__global__ __launch_bounds__(256) void fuse_hG_kernel(float* TG,
                                                      const float* __restrict__ cw,
                                                      const float* __restrict__ ewq,
                                                      const float* __restrict__ ewv,
                                                      float* __restrict__ Gq) {
    const int lane = threadIdx.x & 63;
    const int wave = threadIdx.x >> 6;
    const int t = blockIdx.x * 4 + wave;
    float* Trow = TG + (size_t)t * NRq;
    float h = 0.f;
#pragma unroll
    for (int n = 0; n < Nq; n++) h = fmaf(cw[t * Nq + n], Trow[n * 64 + lane], h);
#pragma unroll
    for (int n = 0; n < Nq; n++) Gq[(size_t)t * NRq + n * 64 + lane] = ewq[t * Nq + n] * h;
#pragma unroll
    for (int n = 0; n < Nq; n++) Trow[n * 64 + lane] = ewv[t * Nq + n] * h;
}

// ---------------------------------------------------------------------------
// MFMA bf16x3 causal flash attention, Q==K.
// grid (S/64, B*H), 256 threads = 4 waves; wave w owns q-rows w*16..w*16+15.
// Fragment conventions identical to gemm_bf16x3:
//   A-frag lane l: m=l&15, k=(l>>4)*8+e (16B contiguous)
//   B-frag lane l: n=l&15, k=(l>>4)*8+e from [N][K]-transposed operand
//     -> K^T's operand layout IS K's natural [key][d]; V needs V^T (pre-built).
//   D-frag lane l reg j: row=(l>>4)*4+j, col=l&15  [m89/m91-verified]
// Softmax in-register: row r lives in the 16 lanes {(r>>2)*16 + 0..15} at reg
// j=r&3 -> shfl_xor(1,2,4,8) row-reduce; m/l/c are per-lane scalars[4].
// P goes through wave-private LDS (bf16 hi/lo) to become the PV A-frag.
#define APITCH 72
__global__ __launch_bounds__(256) void attn_mfma_kernel(const ushort* __restrict__ Qhi,
                                                        const ushort* __restrict__ Qlo,
                                                        const ushort* __restrict__ VThi,
                                                        const ushort* __restrict__ VTlo,
                                                        ushort* __restrict__ AOhi,
                                                        ushort* __restrict__ AOlo) {
    __shared__ ushort Kh[64 * APITCH], Kl[64 * APITCH];  // [key][d]
    __shared__ ushort Vh[64 * APITCH], Vl[64 * APITCH];  // [d][key] (V^T tile)
    __shared__ ushort Ph[4][16 * APITCH], Pl[4][16 * APITCH];  // per-wave P [qrow][key]
    const int tid = threadIdx.x;
    const int lane = tid & 63, w = tid >> 6;
    const int lr = lane & 15, lg = lane >> 4;
    const int qt = blockIdx.x, bh = blockIdx.y;
    const int b = bh >> 4, h = bh & 15;

    // Q A-frags (held in registers for the whole block)
    const size_t qbase = ((size_t)(b * Sq + qt * 64 + w * 16 + lr)) * Dq + h * 64 + lg * 8;
    short8v aqh[2], aql[2];
    aqh[0] = *reinterpret_cast<const short8v*>(Qhi + qbase);
    aqh[1] = *reinterpret_cast<const short8v*>(Qhi + qbase + 32);
    aql[0] = *reinterpret_cast<const short8v*>(Qlo + qbase);
    aql[1] = *reinterpret_cast<const short8v*>(Qlo + qbase + 32);

    float m[4] = {-1e30f, -1e30f, -1e30f, -1e30f};
    float l[4] = {0.f, 0.f, 0.f, 0.f};
    f32x4 out[4];
#pragma unroll
    for (int dt = 0; dt < 4; dt++) out[dt] = (f32x4)(0.f);

    const int srow = tid >> 2;           // 0..63 staging row
    const int sc16 = (tid & 3) * 16;     // 0,16,32,48

    for (int kt = 0; kt <= qt; kt++) {
        __syncthreads();  // prev iter's frag reads done before overwrite
        {   // stage K (natural) and V^T tiles: contiguous 16B copies
            const size_t ksrc = ((size_t)(b * Sq + kt * 64 + srow)) * Dq + h * 64 + sc16;
            const size_t vsrc = ((size_t)(bh * 64 + srow)) * Sq + kt * 64 + sc16;
            const int d0 = srow * APITCH + sc16;
            *reinterpret_cast<short8v*>(&Kh[d0])     = *reinterpret_cast<const short8v*>(Qhi + ksrc);
            *reinterpret_cast<short8v*>(&Kh[d0 + 8]) = *reinterpret_cast<const short8v*>(Qhi + ksrc + 8);
            *reinterpret_cast<short8v*>(&Kl[d0])     = *reinterpret_cast<const short8v*>(Qlo + ksrc);
            *reinterpret_cast<short8v*>(&Kl[d0 + 8]) = *reinterpret_cast<const short8v*>(Qlo + ksrc + 8);
            *reinterpret_cast<short8v*>(&Vh[d0])     = *reinterpret_cast<const short8v*>(VThi + vsrc);
            *reinterpret_cast<short8v*>(&Vh[d0 + 8]) = *reinterpret_cast<const short8v*>(VThi + vsrc + 8);
            *reinterpret_cast<short8v*>(&Vl[d0])     = *reinterpret_cast<const short8v*>(VTlo + vsrc);
            *reinterpret_cast<short8v*>(&Vl[d0 + 8]) = *reinterpret_cast<const short8v*>(VTlo + vsrc + 8);
        }
        __syncthreads();

        // ---- QK^T: S[16 rows][64 cols], cols in 4 ct tiles ----
        f32x4 s[4];
#pragma unroll
        for (int ct = 0; ct < 4; ct++) s[ct] = (f32x4)(0.f);
#pragma unroll
        for (int ct = 0; ct < 4; ct++)
#pragma unroll
            for (int kp = 0; kp < 2; kp++) {
                const int ka = (ct * 16 + lr) * APITCH + kp * 32 + lg * 8;
                const short8v bkh = *reinterpret_cast<const short8v*>(&Kh[ka]);
                const short8v bkl = *reinterpret_cast<const short8v*>(&Kl[ka]);
                s[ct] = __builtin_amdgcn_mfma_f32_16x16x32_bf16(aqh[kp], bkh, s[ct], 0, 0, 0);
                s[ct] = __builtin_amdgcn_mfma_f32_16x16x32_bf16(aqh[kp], bkl, s[ct], 0, 0, 0);
                s[ct] = __builtin_amdgcn_mfma_f32_16x16x32_bf16(aql[kp], bkh, s[ct], 0, 0, 0);
            }
        // scale + causal mask (block-local: row = w*16+lg*4+j, col = ct*16+lr)
#pragma unroll
        for (int ct = 0; ct < 4; ct++)
#pragma unroll
            for (int j = 0; j < 4; j++) {
                float v = s[ct][j] * 0.125f;
                if (kt == qt && (ct * 16 + lr) > (w * 16 + lg * 4 + j)) v = -1e30f;
                s[ct][j] = v;
            }
        // ---- online softmax (in-register) ----
        float c[4];
#pragma unroll
        for (int j = 0; j < 4; j++) {
            float pm = fmaxf(fmaxf(s[0][j], s[1][j]), fmaxf(s[2][j], s[3][j]));
            pm = fmaxf(pm, __shfl_xor(pm, 1));
            pm = fmaxf(pm, __shfl_xor(pm, 2));
            pm = fmaxf(pm, __shfl_xor(pm, 4));
            pm = fmaxf(pm, __shfl_xor(pm, 8));
            const float mn = fmaxf(m[j], pm);
            c[j] = __expf(m[j] - mn);
            m[j] = mn;
        }
        float rs[4] = {0.f, 0.f, 0.f, 0.f};
#pragma unroll
        for (int ct = 0; ct < 4; ct++)
#pragma unroll
            for (int j = 0; j < 4; j++) {
                const float p = __expf(s[ct][j] - m[j]);
                rs[j] += p;
                ushort ph, pl;
                split2(p, ph, pl);
                const int pa = (lg * 4 + j) * APITCH + ct * 16 + lr;
                Ph[w][pa] = ph;
                Pl[w][pa] = pl;
            }
#pragma unroll
        for (int j = 0; j < 4; j++) {
            float t = rs[j];
            t += __shfl_xor(t, 1);
            t += __shfl_xor(t, 2);
            t += __shfl_xor(t, 4);
            t += __shfl_xor(t, 8);
            l[j] = l[j] * c[j] + t;
        }
#pragma unroll
        for (int dt = 0; dt < 4; dt++)
#pragma unroll
            for (int j = 0; j < 4; j++) out[dt][j] *= c[j];
        // ---- PV: out[16 rows][64 d] += P[16][64] @ V[64 keys][64 d] ----
        // (wave-private P: within-wave LDS RAW, no barrier needed)
#pragma unroll
        for (int kp = 0; kp < 2; kp++) {
            const int pa = lr * APITCH + kp * 32 + lg * 8;
            const short8v pah = *reinterpret_cast<const short8v*>(&Ph[w][pa]);
            const short8v pal = *reinterpret_cast<const short8v*>(&Pl[w][pa]);
#pragma unroll
            for (int dt = 0; dt < 4; dt++) {
                const int va = (dt * 16 + lr) * APITCH + kp * 32 + lg * 8;
                const short8v bvh = *reinterpret_cast<const short8v*>(&Vh[va]);
                const short8v bvl = *reinterpret_cast<const short8v*>(&Vl[va]);
                out[dt] = __builtin_amdgcn_mfma_f32_16x16x32_bf16(pah, bvh, out[dt], 0, 0, 0);
                out[dt] = __builtin_amdgcn_mfma_f32_16x16x32_bf16(pah, bvl, out[dt], 0, 0, 0);
                out[dt] = __builtin_amdgcn_mfma_f32_16x16x32_bf16(pal, bvh, out[dt], 0, 0, 0);
            }
        }
    }
    // ---- epilogue: normalize + split-write bf16 hi/lo for GEMM4 ----
#pragma unroll
    for (int j = 0; j < 4; j++) l[j] = 1.f / l[j];
#pragma unroll
    for (int dt = 0; dt < 4; dt++)
#pragma unroll
        for (int j = 0; j < 4; j++) {
            const float v = out[dt][j] * l[j];
            ushort vh, vl;
            split2(v, vh, vl);
            const size_t o = ((size_t)(b * Sq + qt * 64 + w * 16 + lg * 4 + j)) * Dq
                             + h * 64 + dt * 16 + lr;
            AOhi[o] = vh;
            AOlo[o] = vl;
        }
}

// ---------------------------------------------------------------------------
extern "C" void kernel_launch(void* const* d_in, const int* in_sizes, int n_in,
                              void* d_out, int out_size, void* d_ws, size_t ws_size,
                              hipStream_t stream) {
    (void)in_sizes; (void)n_in; (void)out_size; (void)ws_size;
    const float* x   = (const float*)d_in[0];  // [B,S,D]
    const float* cw  = (const float*)d_in[1];  // [B,S,N]
    const float* ewq = (const float*)d_in[2];  // [B,S,N]
    const float* ewv = (const float*)d_in[3];  // [B,S,N]
    const float* cn  = (const float*)d_in[4];  // [N,D,R]
    const float* enq = (const float*)d_in[5];  // [N,R,D] == flat [NR,D]
    const float* env = (const float*)d_in[6];  // [N,R,D] == flat [NR,D]
    const float* wo  = (const float*)d_in[7];  // [D,D]
    float* out = (float*)d_out;
    float* ws  = (float*)d_ws;

    // Workspace 112 MB with phase-based region reuse:
    //   Tg   (32MB): T fp32 -> Gv fp32 (in place) -> QShi/QSlo bf16
    //   GqQ  (32MB): Gq fp32 -> Q fp32 (GEMM2 overwrites) -> VThi/VTlo bf16
    //   SA   (32MB): X split -> Gv split -> Gq split -> attn-out split
    //   smalls (16MB): C_all^T / Eqk^T / Ev^T / W_O  hi+lo
    // V fp32 lives in d_out (dead until GEMM4 overwrites it).
    const size_t MEG = 1024 * 1024;
    float* Tg  = ws;
    float* GqQ = ws + 8 * MEG;
    float* Vf  = out;
    ushort* us = (ushort*)(ws + 16 * MEG);
    ushort* SAhi = us;
    ushort* SAlo = us + 8 * MEG;
    ushort* cBhi = us + 16 * MEG;
    ushort* cBlo = us + 17 * MEG;
    ushort* eqBhi = us + 18 * MEG;
    ushort* eqBlo = us + 19 * MEG;
    ushort* evBhi = us + 20 * MEG;
    ushort* evBlo = us + 21 * MEG;
    ushort* woBhi = us + 22 * MEG;
    ushort* woBlo = us + 23 * MEG;
    ushort* QShi = (ushort*)Tg;          // after Tg fp32 is dead
    ushort* QSlo = QShi + 8 * MEG;
    ushort* VThi = (ushort*)GqQ;         // after GqQ fp32 is dead
    ushort* VTlo = VThi + 8 * MEG;

    // ---- operand prep ----
    split_kernel<<<8192, 256, 0, stream>>>(x, SAhi, SAlo);              // X
    callT_split_kernel<<<4096, 256, 0, stream>>>(cn, cBhi, cBlo);       // C_all^T
    transpose_split_kernel<<<256, 256, 0, stream>>>(enq, eqBhi, eqBlo); // Eqk^T
    transpose_split_kernel<<<256, 256, 0, stream>>>(env, evBhi, evBlo); // Ev^T
    split_kernel<<<1024, 256, 0, stream>>>(wo, woBhi, woBlo);           // W_O (== B^T already)

    const dim3 gg(8, 64);  // N/128, M/128
    gemm_bf16x3<<<gg, 256, 0, stream>>>(SAhi, SAlo, cBhi, cBlo, Tg, Mq, NRq, Dq);    // T = X@C_all
    fuse_hG_kernel<<<2048, 256, 0, stream>>>(Tg, cw, ewq, ewv, GqQ);                 // h, Gq; Gv over T
    split_kernel<<<8192, 256, 0, stream>>>(Tg, SAhi, SAlo);                          // Gv split (X dead)
    gemm_bf16x3<<<gg, 256, 0, stream>>>(SAhi, SAlo, evBhi, evBlo, Vf, Mq, Dq, NRq);  // V = Gv@Ev -> d_out
    split_kernel<<<8192, 256, 0, stream>>>(GqQ, SAhi, SAlo);                         // Gq split (Gv split dead)
    gemm_bf16x3<<<gg, 256, 0, stream>>>(SAhi, SAlo, eqBhi, eqBlo, GqQ, Mq, Dq, NRq); // Q = Gq@Eqk (over Gq)
    split_kernel<<<8192, 256, 0, stream>>>(GqQ, QShi, QSlo);                         // Q split -> Tg region
    vt_split_kernel<<<dim3(32, 64), 256, 0, stream>>>(Vf, VThi, VTlo);               // V^T split -> GqQ region
    attn_mfma_kernel<<<dim3(32, 64), 256, 0, stream>>>(QShi, QSlo, VThi, VTlo,
                                                       SAhi, SAlo);                  // attn -> SA (bf16)
    gemm_bf16x3<<<gg, 256, 0, stream>>>(SAhi, SAlo, woBhi, woBlo, out, Mq, Dq, Dq);  // Y = attn@W_O^T
}

// Round 7
// 627.925 us; speedup vs baseline: 1.3017x; 1.3017x over previous
//
#include <hip/hip_runtime.h>
#include <hip/hip_bf16.h>
#include <math.h>

// Problem constants (B,S,D,H,R,N = 4,2048,1024,16,64,16)
#define Bq 4
#define Sq 2048
#define Dq 1024
#define Hq 16
#define Rq 64
#define Nq 16
#define DHq 64
#define Mq (Bq * Sq)   // 8192 tokens
#define NRq (Nq * Rq)  // 1024

static_assert(NRq == Dq, "layout assumption");

typedef __attribute__((ext_vector_type(8))) short short8v;  // 8 bf16 (4 VGPRs)
typedef __attribute__((ext_vector_type(4))) float f32x4;    // 4 fp32 acc

// ---------------------------------------------------------------------------
// bf16 split helpers: x ~= hi + lo with ~2^-17 relative error.
__device__ inline ushort bf16_rne(float x) {
    __hip_bfloat16 b = __float2bfloat16(x);
    return *reinterpret_cast<ushort*>(&b);
}
__device__ inline float bf16_to_f(ushort u) {
    union { unsigned int i; float f; } c;
    c.i = ((unsigned int)u) << 16;
    return c.f;
}
__device__ inline void split2(float x, ushort& h, ushort& l) {
    h = bf16_rne(x);
    l = bf16_rne(x - bf16_to_f(h));
}

// Generic elementwise split (with optional scale): fp32[n]*scale -> hi/lo bf16[n].
__global__ __launch_bounds__(256) void split_kernel(const float* __restrict__ in,
                                                    ushort* __restrict__ hi,
                                                    ushort* __restrict__ lo,
                                                    float scale) {
    const int i = blockIdx.x * 256 + threadIdx.x;
    const float4 v = *reinterpret_cast<const float4*>(&in[(size_t)i * 4]);
    ushort4 h4, l4;
    split2(v.x * scale, h4.x, l4.x);
    split2(v.y * scale, h4.y, l4.y);
    split2(v.z * scale, h4.z, l4.z);
    split2(v.w * scale, h4.w, l4.w);
    *reinterpret_cast<ushort4*>(&hi[(size_t)i * 4]) = h4;
    *reinterpret_cast<ushort4*>(&lo[(size_t)i * 4]) = l4;
}

// C_all^T split: out[nr][d] = cn[n][d][r]  (cn: [N,D,R] fp32).
__global__ __launch_bounds__(256) void callT_split_kernel(const float* __restrict__ cn,
                                                          ushort* __restrict__ bhi,
                                                          ushort* __restrict__ blo) {
    const int idx = blockIdx.x * 256 + threadIdx.x;  // over 1M
    const int nr = idx >> 10, d = idx & 1023;
    const int n = nr >> 6, r = nr & 63;
    const float v = cn[((size_t)(n << 10) + d) * 64 + r];
    ushort h, l;
    split2(v, h, l);
    bhi[idx] = h;
    blo[idx] = l;
}

// Transpose+split 1024x1024: out[n][k] = in[k][n], fp32 -> hi/lo bf16. 64x64 tiles.
__global__ __launch_bounds__(256) void transpose_split_kernel(const float* __restrict__ in,
                                                              ushort* __restrict__ bhi,
                                                              ushort* __restrict__ blo) {
    __shared__ float tl[64][65];
    const int bx = blockIdx.x;        // 256 blocks = 16x16 tiles
    const int tn0 = (bx & 15) * 64;   // input col block
    const int tk0 = (bx >> 4) * 64;   // input row block
    const int r0 = threadIdx.x >> 4;  // 0..15
    const int c4 = (threadIdx.x & 15) * 4;
#pragma unroll
    for (int p = 0; p < 4; p++) {
        const int row = r0 + p * 16;
        const float4 v = *reinterpret_cast<const float4*>(&in[(size_t)(tk0 + row) * 1024 + tn0 + c4]);
        tl[row][c4 + 0] = v.x; tl[row][c4 + 1] = v.y;
        tl[row][c4 + 2] = v.z; tl[row][c4 + 3] = v.w;
    }
    __syncthreads();
#pragma unroll
    for (int p = 0; p < 4; p++) {
        const int orow = r0 + p * 16;  // output row (= input col)
        ushort4 h4, l4;
        split2(tl[c4 + 0][orow], h4.x, l4.x);
        split2(tl[c4 + 1][orow], h4.y, l4.y);
        split2(tl[c4 + 2][orow], h4.z, l4.z);
        split2(tl[c4 + 3][orow], h4.w, l4.w);
        const size_t o = (size_t)(tn0 + orow) * 1024 + tk0 + c4;
        *reinterpret_cast<ushort4*>(&bhi[o]) = h4;
        *reinterpret_cast<ushort4*>(&blo[o]) = l4;
    }
}

// V^T split: Vf fp32 [tok][h*64+d] -> VT hi/lo bf16 [bh][d][s(2048)].
__global__ __launch_bounds__(256) void vt_split_kernel(const float* __restrict__ Vf,
                                                       ushort* __restrict__ vthi,
                                                       ushort* __restrict__ vtlo) {
    __shared__ float tl[64][65];
    const int st = blockIdx.x, bh = blockIdx.y;
    const int b = bh >> 4, h = bh & 15;
    const int i = threadIdx.x >> 2;          // 0..63
    const int c16 = (threadIdx.x & 3) * 16;  // 0,16,32,48
#pragma unroll
    for (int p = 0; p < 4; p++) {
        const float4 v = *reinterpret_cast<const float4*>(
            &Vf[((size_t)(b * Sq + st * 64 + i)) * Dq + h * 64 + c16 + p * 4]);
        tl[i][c16 + p * 4 + 0] = v.x; tl[i][c16 + p * 4 + 1] = v.y;
        tl[i][c16 + p * 4 + 2] = v.z; tl[i][c16 + p * 4 + 3] = v.w;
    }
    __syncthreads();
    const size_t obase = ((size_t)(bh * 64 + i)) * Sq + st * 64 + c16;
#pragma unroll
    for (int p = 0; p < 4; p++) {
        ushort4 h4, l4;
        split2(tl[c16 + p * 4 + 0][i], h4.x, l4.x);
        split2(tl[c16 + p * 4 + 1][i], h4.y, l4.y);
        split2(tl[c16 + p * 4 + 2][i], h4.z, l4.z);
        split2(tl[c16 + p * 4 + 3][i], h4.w, l4.w);
        *reinterpret_cast<ushort4*>(&vthi[obase + p * 4]) = h4;
        *reinterpret_cast<ushort4*>(&vtlo[obase + p * 4]) = l4;
    }
}

// ---------------------------------------------------------------------------
// MFMA bf16x3 GEMM (audited; unchanged from passing round-5 build).
#define LPITCH 40
__global__ __launch_bounds__(256) void gemm_bf16x3(const ushort* __restrict__ Ahi,
                                                   const ushort* __restrict__ Alo,
                                                   const ushort* __restrict__ Bthi,
                                                   const ushort* __restrict__ Btlo,
                                                   float* __restrict__ C,
                                                   int M, int N, int K) {
    __shared__ ushort lAhi[128 * LPITCH];
    __shared__ ushort lAlo[128 * LPITCH];
    __shared__ ushort lBhi[128 * LPITCH];
    __shared__ ushort lBlo[128 * LPITCH];
    const int tid = threadIdx.x;
    const int lane = tid & 63;
    const int wave = tid >> 6;
    const int wr = wave >> 1, wc = wave & 1;
    const int row0 = blockIdx.y * 128, col0 = blockIdx.x * 128;

    const int srow = tid >> 2;
    const int spart = tid & 3;
    const int lrow = lane & 15;
    const int kgrp = lane >> 4;

    f32x4 acc[4][4];
#pragma unroll
    for (int i = 0; i < 4; i++)
#pragma unroll
        for (int j = 0; j < 4; j++) acc[i][j] = (f32x4)(0.f);

    for (int k0 = 0; k0 < K; k0 += 32) {
        const size_t ga0 = (size_t)(row0 + srow) * K + k0 + spart * 8;
        const size_t ga1 = ga0 + (size_t)64 * K;
        const size_t gb0 = (size_t)(col0 + srow) * K + k0 + spart * 8;
        const size_t gb1 = gb0 + (size_t)64 * K;
        const short8v ah0 = *reinterpret_cast<const short8v*>(Ahi + ga0);
        const short8v ah1 = *reinterpret_cast<const short8v*>(Ahi + ga1);
        const short8v al0 = *reinterpret_cast<const short8v*>(Alo + ga0);
        const short8v al1 = *reinterpret_cast<const short8v*>(Alo + ga1);
        const short8v bh0 = *reinterpret_cast<const short8v*>(Bthi + gb0);
        const short8v bh1 = *reinterpret_cast<const short8v*>(Bthi + gb1);
        const short8v bl0 = *reinterpret_cast<const short8v*>(Btlo + gb0);
        const short8v bl1 = *reinterpret_cast<const short8v*>(Btlo + gb1);
        __syncthreads();
        const int s0 = srow * LPITCH + spart * 8;
        const int s1 = (srow + 64) * LPITCH + spart * 8;
        *reinterpret_cast<short8v*>(&lAhi[s0]) = ah0;
        *reinterpret_cast<short8v*>(&lAhi[s1]) = ah1;
        *reinterpret_cast<short8v*>(&lAlo[s0]) = al0;
        *reinterpret_cast<short8v*>(&lAlo[s1]) = al1;
        *reinterpret_cast<short8v*>(&lBhi[s0]) = bh0;
        *reinterpret_cast<short8v*>(&lBhi[s1]) = bh1;
        *reinterpret_cast<short8v*>(&lBlo[s0]) = bl0;
        *reinterpret_cast<short8v*>(&lBlo[s1]) = bl1;
        __syncthreads();
        short8v afh[4], afl[4], bfh[4], bfl[4];
#pragma unroll
        for (int im = 0; im < 4; im++) {
            const int a = (wr * 64 + im * 16 + lrow) * LPITCH + kgrp * 8;
            afh[im] = *reinterpret_cast<const short8v*>(&lAhi[a]);
            afl[im] = *reinterpret_cast<const short8v*>(&lAlo[a]);
        }
#pragma unroll
        for (int in = 0; in < 4; in++) {
            const int bb = (wc * 64 + in * 16 + lrow) * LPITCH + kgrp * 8;
            bfh[in] = *reinterpret_cast<const short8v*>(&lBhi[bb]);
            bfl[in] = *reinterpret_cast<const short8v*>(&lBlo[bb]);
        }
#pragma unroll
        for (int im = 0; im < 4; im++)
#pragma unroll
            for (int in = 0; in < 4; in++) {
                acc[im][in] = __builtin_amdgcn_mfma_f32_16x16x32_bf16(afh[im], bfh[in], acc[im][in], 0, 0, 0);
                acc[im][in] = __builtin_amdgcn_mfma_f32_16x16x32_bf16(afh[im], bfl[in], acc[im][in], 0, 0, 0);
                acc[im][in] = __builtin_amdgcn_mfma_f32_16x16x32_bf16(afl[im], bfh[in], acc[im][in], 0, 0, 0);
            }
    }
#pragma unroll
    for (int im = 0; im < 4; im++) {
        const int orow = row0 + wr * 64 + im * 16 + kgrp * 4;
#pragma unroll
        for (int in = 0; in < 4; in++) {
            const int ocol = col0 + wc * 64 + in * 16 + lrow;
#pragma unroll
            for (int j = 0; j < 4; j++) C[(size_t)(orow + j) * N + ocol] = acc[im][in][j];
        }
    }
}

// ---------------------------------------------------------------------------
// h/Gq/Gv fuse (unchanged).
__global__ __launch_bounds__(256) void fuse_hG_kernel(float* TG,
                                                      const float* __restrict__ cw,
                                                      const float* __restrict__ ewq,
                                                      const float* __restrict__ ewv,
                                                      float* __restrict__ Gq) {
    const int lane = threadIdx.x & 63;
    const int wave = threadIdx.x >> 6;
    const int t = blockIdx.x * 4 + wave;
    float* Trow = TG + (size_t)t * NRq;
    float h = 0.f;
#pragma unroll
    for (int n = 0; n < Nq; n++) h = fmaf(cw[t * Nq + n], Trow[n * 64 + lane], h);
#pragma unroll
    for (int n = 0; n < Nq; n++) Gq[(size_t)t * NRq + n * 64 + lane] = ewq[t * Nq + n] * h;
#pragma unroll
    for (int n = 0; n < Nq; n++) Trow[n * 64 + lane] = ewv[t * Nq + n] * h;
}

// ---------------------------------------------------------------------------
// MFMA attention v2. Changes vs v1 (427us, MfmaUtil 10%, Occ 10%, 19.5M conflicts):
//  - LDS 54->43.5 KB (pitch 68 K/V, 76 P, P hi-only)  => 3 blocks/CU
//  - causal pairing: grid (16,64); block x does qt={x, 31-x} = 33 iters flat
//  - T14 async-stage: issue next-tile global loads before current compute
//  - Q pre-scaled by sqrt(1/8) at split (Q==K => product carries 1/8)
//  - P stored bf16 hi-only (adds ~0.01 abs err; measured headroom 0.125)
#define APITCH 68
#define PPITCH 76
#define STAGE_ISSUE(kt_, R)                                                          \
    do {                                                                             \
        const size_t ksrc = ((size_t)(b * Sq + (kt_) * 64 + srow)) * Dq + h * 64 + sc16; \
        const size_t vsrc = ((size_t)(bh * 64 + srow)) * Sq + (kt_) * 64 + sc16;     \
        R[0] = *reinterpret_cast<const short8v*>(Qhi + ksrc);                        \
        R[1] = *reinterpret_cast<const short8v*>(Qhi + ksrc + 8);                    \
        R[2] = *reinterpret_cast<const short8v*>(Qlo + ksrc);                        \
        R[3] = *reinterpret_cast<const short8v*>(Qlo + ksrc + 8);                    \
        R[4] = *reinterpret_cast<const short8v*>(VThi + vsrc);                       \
        R[5] = *reinterpret_cast<const short8v*>(VThi + vsrc + 8);                   \
        R[6] = *reinterpret_cast<const short8v*>(VTlo + vsrc);                       \
        R[7] = *reinterpret_cast<const short8v*>(VTlo + vsrc + 8);                   \
    } while (0)
#define STAGE_WRITE(R)                                        \
    do {                                                      \
        const int d0 = srow * APITCH + sc16;                  \
        *reinterpret_cast<short8v*>(&Kh[d0])     = R[0];      \
        *reinterpret_cast<short8v*>(&Kh[d0 + 8]) = R[1];      \
        *reinterpret_cast<short8v*>(&Kl[d0])     = R[2];      \
        *reinterpret_cast<short8v*>(&Kl[d0 + 8]) = R[3];      \
        *reinterpret_cast<short8v*>(&Vh[d0])     = R[4];      \
        *reinterpret_cast<short8v*>(&Vh[d0 + 8]) = R[5];      \
        *reinterpret_cast<short8v*>(&Vl[d0])     = R[6];      \
        *reinterpret_cast<short8v*>(&Vl[d0 + 8]) = R[7];      \
    } while (0)

__global__ __launch_bounds__(256) void attn_mfma_kernel(const ushort* __restrict__ Qhi,
                                                        const ushort* __restrict__ Qlo,
                                                        const ushort* __restrict__ VThi,
                                                        const ushort* __restrict__ VTlo,
                                                        ushort* __restrict__ AOhi,
                                                        ushort* __restrict__ AOlo) {
    __shared__ ushort Kh[64 * APITCH], Kl[64 * APITCH];   // [key][d]
    __shared__ ushort Vh[64 * APITCH], Vl[64 * APITCH];   // [d][key] (V^T tile)
    __shared__ ushort Ph[4][16 * PPITCH];                 // per-wave P (hi only)
    const int tid = threadIdx.x;
    const int lane = tid & 63, w = tid >> 6;
    const int lr = lane & 15, lg = lane >> 4;
    const int bh = blockIdx.y;
    const int b = bh >> 4, h = bh & 15;
    const int srow = tid >> 2;           // staging row 0..63
    const int sc16 = (tid & 3) * 16;     // staging col (ushorts)

#pragma unroll 1
    for (int pass = 0; pass < 2; pass++) {
        const int qt = pass ? 31 - blockIdx.x : blockIdx.x;
        // Q A-frags (pre-scaled by sqrt(1/8)); held in regs for the whole pass
        const size_t qbase = ((size_t)(b * Sq + qt * 64 + w * 16 + lr)) * Dq + h * 64 + lg * 8;
        const short8v aqh0 = *reinterpret_cast<const short8v*>(Qhi + qbase);
        const short8v aqh1 = *reinterpret_cast<const short8v*>(Qhi + qbase + 32);
        const short8v aql0 = *reinterpret_cast<const short8v*>(Qlo + qbase);
        const short8v aql1 = *reinterpret_cast<const short8v*>(Qlo + qbase + 32);

        float m[4] = {-1e30f, -1e30f, -1e30f, -1e30f};
        float l[4] = {0.f, 0.f, 0.f, 0.f};
        f32x4 out[4];
#pragma unroll
        for (int dt = 0; dt < 4; dt++) out[dt] = (f32x4)(0.f);

        // prologue: stage kt=0
        {
            short8v R[8];
            STAGE_ISSUE(0, R);
            __syncthreads();  // prev pass readers done before overwrite
            STAGE_WRITE(R);
        }
        __syncthreads();

        for (int kt = 0; kt <= qt; kt++) {
            const bool more = kt < qt;
            short8v NX[8];
            if (more) STAGE_ISSUE(kt + 1, NX);  // T14: issue early, write late

            // ---- QK^T: S[16 q-rows][64 keys] ----
            f32x4 s[4];
#pragma unroll
            for (int ct = 0; ct < 4; ct++) s[ct] = (f32x4)(0.f);
#pragma unroll
            for (int ct = 0; ct < 4; ct++) {
                {
                    const int ka = (ct * 16 + lr) * APITCH + lg * 8;
                    const short8v bkh = *reinterpret_cast<const short8v*>(&Kh[ka]);
                    const short8v bkl = *reinterpret_cast<const short8v*>(&Kl[ka]);
                    s[ct] = __builtin_amdgcn_mfma_f32_16x16x32_bf16(aqh0, bkh, s[ct], 0, 0, 0);
                    s[ct] = __builtin_amdgcn_mfma_f32_16x16x32_bf16(aqh0, bkl, s[ct], 0, 0, 0);
                    s[ct] = __builtin_amdgcn_mfma_f32_16x16x32_bf16(aql0, bkh, s[ct], 0, 0, 0);
                }
                {
                    const int ka = (ct * 16 + lr) * APITCH + 32 + lg * 8;
                    const short8v bkh = *reinterpret_cast<const short8v*>(&Kh[ka]);
                    const short8v bkl = *reinterpret_cast<const short8v*>(&Kl[ka]);
                    s[ct] = __builtin_amdgcn_mfma_f32_16x16x32_bf16(aqh1, bkh, s[ct], 0, 0, 0);
                    s[ct] = __builtin_amdgcn_mfma_f32_16x16x32_bf16(aqh1, bkl, s[ct], 0, 0, 0);
                    s[ct] = __builtin_amdgcn_mfma_f32_16x16x32_bf16(aql1, bkh, s[ct], 0, 0, 0);
                }
            }
            if (kt == qt) {  // causal mask on diagonal tile only
#pragma unroll
                for (int ct = 0; ct < 4; ct++)
#pragma unroll
                    for (int j = 0; j < 4; j++)
                        if ((ct * 16 + lr) > (w * 16 + lg * 4 + j)) s[ct][j] = -1e30f;
            }
            // ---- online softmax (in-register; rows = 16 consecutive lanes) ----
            float c[4];
#pragma unroll
            for (int j = 0; j < 4; j++) {
                float pm = fmaxf(fmaxf(s[0][j], s[1][j]), fmaxf(s[2][j], s[3][j]));
                pm = fmaxf(pm, __shfl_xor(pm, 1));
                pm = fmaxf(pm, __shfl_xor(pm, 2));
                pm = fmaxf(pm, __shfl_xor(pm, 4));
                pm = fmaxf(pm, __shfl_xor(pm, 8));
                const float mn = fmaxf(m[j], pm);
                c[j] = __expf(m[j] - mn);
                m[j] = mn;
            }
            float rs[4] = {0.f, 0.f, 0.f, 0.f};
#pragma unroll
            for (int ct = 0; ct < 4; ct++)
#pragma unroll
                for (int j = 0; j < 4; j++) {
                    const float p = __expf(s[ct][j] - m[j]);
                    rs[j] += p;
                    Ph[w][(lg * 4 + j) * PPITCH + ct * 16 + lr] = bf16_rne(p);
                }
#pragma unroll
            for (int j = 0; j < 4; j++) {
                float t = rs[j];
                t += __shfl_xor(t, 1);
                t += __shfl_xor(t, 2);
                t += __shfl_xor(t, 4);
                t += __shfl_xor(t, 8);
                l[j] = l[j] * c[j] + t;
            }
#pragma unroll
            for (int dt = 0; dt < 4; dt++)
#pragma unroll
                for (int j = 0; j < 4; j++) out[dt][j] *= c[j];
            // ---- PV (P hi-only; wave-private LDS, same-wave ordering) ----
#pragma unroll
            for (int kp = 0; kp < 2; kp++) {
                const short8v pah = *reinterpret_cast<const short8v*>(
                    &Ph[w][lr * PPITCH + kp * 32 + lg * 8]);
#pragma unroll
                for (int dt = 0; dt < 4; dt++) {
                    const int va = (dt * 16 + lr) * APITCH + kp * 32 + lg * 8;
                    const short8v bvh = *reinterpret_cast<const short8v*>(&Vh[va]);
                    const short8v bvl = *reinterpret_cast<const short8v*>(&Vl[va]);
                    out[dt] = __builtin_amdgcn_mfma_f32_16x16x32_bf16(pah, bvh, out[dt], 0, 0, 0);
                    out[dt] = __builtin_amdgcn_mfma_f32_16x16x32_bf16(pah, bvl, out[dt], 0, 0, 0);
                }
            }
            __syncthreads();             // all waves done reading K/V LDS
            if (more) STAGE_WRITE(NX);   // write next tile
            __syncthreads();
        }
        // ---- epilogue: normalize + split-write bf16 hi/lo for GEMM4 ----
#pragma unroll
        for (int j = 0; j < 4; j++) l[j] = 1.f / l[j];
#pragma unroll
        for (int dt = 0; dt < 4; dt++)
#pragma unroll
            for (int j = 0; j < 4; j++) {
                const float v = out[dt][j] * l[j];
                ushort vh, vl;
                split2(v, vh, vl);
                const size_t o = ((size_t)(b * Sq + qt * 64 + w * 16 + lg * 4 + j)) * Dq
                                 + h * 64 + dt * 16 + lr;
                AOhi[o] = vh;
                AOlo[o] = vl;
            }
    }
}

// ---------------------------------------------------------------------------
extern "C" void kernel_launch(void* const* d_in, const int* in_sizes, int n_in,
                              void* d_out, int out_size, void* d_ws, size_t ws_size,
                              hipStream_t stream) {
    (void)in_sizes; (void)n_in; (void)out_size; (void)ws_size;
    const float* x   = (const float*)d_in[0];
    const float* cw  = (const float*)d_in[1];
    const float* ewq = (const float*)d_in[2];
    const float* ewv = (const float*)d_in[3];
    const float* cn  = (const float*)d_in[4];
    const float* enq = (const float*)d_in[5];
    const float* env = (const float*)d_in[6];
    const float* wo  = (const float*)d_in[7];
    float* out = (float*)d_out;
    float* ws  = (float*)d_ws;

    // Workspace 112 MB, phase-based reuse (identical to passing round-5 plan).
    const size_t MEG = 1024 * 1024;
    float* Tg  = ws;
    float* GqQ = ws + 8 * MEG;
    float* Vf  = out;                    // V fp32 in d_out (dead until GEMM4)
    ushort* us = (ushort*)(ws + 16 * MEG);
    ushort* SAhi = us;
    ushort* SAlo = us + 8 * MEG;
    ushort* cBhi = us + 16 * MEG;
    ushort* cBlo = us + 17 * MEG;
    ushort* eqBhi = us + 18 * MEG;
    ushort* eqBlo = us + 19 * MEG;
    ushort* evBhi = us + 20 * MEG;
    ushort* evBlo = us + 21 * MEG;
    ushort* woBhi = us + 22 * MEG;
    ushort* woBlo = us + 23 * MEG;
    ushort* QShi = (ushort*)Tg;          // after Tg fp32 dead
    ushort* QSlo = QShi + 8 * MEG;
    ushort* VThi = (ushort*)GqQ;         // after GqQ fp32 dead
    ushort* VTlo = VThi + 8 * MEG;

    split_kernel<<<8192, 256, 0, stream>>>(x, SAhi, SAlo, 1.0f);
    callT_split_kernel<<<4096, 256, 0, stream>>>(cn, cBhi, cBlo);
    transpose_split_kernel<<<256, 256, 0, stream>>>(enq, eqBhi, eqBlo);
    transpose_split_kernel<<<256, 256, 0, stream>>>(env, evBhi, evBlo);
    split_kernel<<<1024, 256, 0, stream>>>(wo, woBhi, woBlo, 1.0f);

    const dim3 gg(8, 64);
    gemm_bf16x3<<<gg, 256, 0, stream>>>(SAhi, SAlo, cBhi, cBlo, Tg, Mq, NRq, Dq);    // T = X@C_all
    fuse_hG_kernel<<<2048, 256, 0, stream>>>(Tg, cw, ewq, ewv, GqQ);                 // h, Gq; Gv over T
    split_kernel<<<8192, 256, 0, stream>>>(Tg, SAhi, SAlo, 1.0f);                    // Gv split
    gemm_bf16x3<<<gg, 256, 0, stream>>>(SAhi, SAlo, evBhi, evBlo, Vf, Mq, Dq, NRq);  // V = Gv@Ev
    split_kernel<<<8192, 256, 0, stream>>>(GqQ, SAhi, SAlo, 1.0f);                   // Gq split
    gemm_bf16x3<<<gg, 256, 0, stream>>>(SAhi, SAlo, eqBhi, eqBlo, GqQ, Mq, Dq, NRq); // Q = Gq@Eqk
    // Q split pre-scaled by sqrt(1/8): Q==K so the QK product carries 1/8.
    split_kernel<<<8192, 256, 0, stream>>>(GqQ, QShi, QSlo, 0.35355339f);
    vt_split_kernel<<<dim3(32, 64), 256, 0, stream>>>(Vf, VThi, VTlo);
    attn_mfma_kernel<<<dim3(16, 64), 256, 0, stream>>>(QShi, QSlo, VThi, VTlo,
                                                       SAhi, SAlo);                  // attn -> SA bf16
    gemm_bf16x3<<<gg, 256, 0, stream>>>(SAhi, SAlo, woBhi, woBlo, out, Mq, Dq, Dq);  // Y = attn@W_O^T
}

// Round 9
// 602.333 us; speedup vs baseline: 1.3570x; 1.0425x over previous
//
#include <hip/hip_runtime.h>
#include <hip/hip_bf16.h>
#include <math.h>

// Problem constants (B,S,D,H,R,N = 4,2048,1024,16,64,16)
#define Bq 4
#define Sq 2048
#define Dq 1024
#define Hq 16
#define Rq 64
#define Nq 16
#define DHq 64
#define Mq (Bq * Sq)   // 8192 tokens
#define NRq (Nq * Rq)  // 1024

static_assert(NRq == Dq, "layout assumption");

typedef __attribute__((ext_vector_type(8))) short short8v;  // 8 bf16 (4 VGPRs)
typedef __attribute__((ext_vector_type(4))) float f32x4;    // 4 fp32 acc

// ---------------------------------------------------------------------------
// bf16 split helpers: x ~= hi + lo with ~2^-17 relative error.
__device__ inline ushort bf16_rne(float x) {
    __hip_bfloat16 b = __float2bfloat16(x);
    return *reinterpret_cast<ushort*>(&b);
}
__device__ inline float bf16_to_f(ushort u) {
    union { unsigned int i; float f; } c;
    c.i = ((unsigned int)u) << 16;
    return c.f;
}
__device__ inline void split2(float x, ushort& h, ushort& l) {
    h = bf16_rne(x);
    l = bf16_rne(x - bf16_to_f(h));
}

// Generic elementwise split (with optional scale): fp32[n]*scale -> hi/lo bf16[n].
__global__ __launch_bounds__(256) void split_kernel(const float* __restrict__ in,
                                                    ushort* __restrict__ hi,
                                                    ushort* __restrict__ lo,
                                                    float scale) {
    const int i = blockIdx.x * 256 + threadIdx.x;
    const float4 v = *reinterpret_cast<const float4*>(&in[(size_t)i * 4]);
    ushort4 h4, l4;
    split2(v.x * scale, h4.x, l4.x);
    split2(v.y * scale, h4.y, l4.y);
    split2(v.z * scale, h4.z, l4.z);
    split2(v.w * scale, h4.w, l4.w);
    *reinterpret_cast<ushort4*>(&hi[(size_t)i * 4]) = h4;
    *reinterpret_cast<ushort4*>(&lo[(size_t)i * 4]) = l4;
}

// C_all^T split: out[nr][d] = cn[n][d][r]  (cn: [N,D,R] fp32).
__global__ __launch_bounds__(256) void callT_split_kernel(const float* __restrict__ cn,
                                                          ushort* __restrict__ bhi,
                                                          ushort* __restrict__ blo) {
    const int idx = blockIdx.x * 256 + threadIdx.x;  // over 1M
    const int nr = idx >> 10, d = idx & 1023;
    const int n = nr >> 6, r = nr & 63;
    const float v = cn[((size_t)(n << 10) + d) * 64 + r];
    ushort h, l;
    split2(v, h, l);
    bhi[idx] = h;
    blo[idx] = l;
}

// Transpose+split 1024x1024: out[n][k] = in[k][n], fp32 -> hi/lo bf16. 64x64 tiles.
__global__ __launch_bounds__(256) void transpose_split_kernel(const float* __restrict__ in,
                                                              ushort* __restrict__ bhi,
                                                              ushort* __restrict__ blo) {
    __shared__ float tl[64][65];
    const int bx = blockIdx.x;        // 256 blocks = 16x16 tiles
    const int tn0 = (bx & 15) * 64;   // input col block
    const int tk0 = (bx >> 4) * 64;   // input row block
    const int r0 = threadIdx.x >> 4;  // 0..15
    const int c4 = (threadIdx.x & 15) * 4;
#pragma unroll
    for (int p = 0; p < 4; p++) {
        const int row = r0 + p * 16;
        const float4 v = *reinterpret_cast<const float4*>(&in[(size_t)(tk0 + row) * 1024 + tn0 + c4]);
        tl[row][c4 + 0] = v.x; tl[row][c4 + 1] = v.y;
        tl[row][c4 + 2] = v.z; tl[row][c4 + 3] = v.w;
    }
    __syncthreads();
#pragma unroll
    for (int p = 0; p < 4; p++) {
        const int orow = r0 + p * 16;  // output row (= input col)
        ushort4 h4, l4;
        split2(tl[c4 + 0][orow], h4.x, l4.x);
        split2(tl[c4 + 1][orow], h4.y, l4.y);
        split2(tl[c4 + 2][orow], h4.z, l4.z);
        split2(tl[c4 + 3][orow], h4.w, l4.w);
        const size_t o = (size_t)(tn0 + orow) * 1024 + tk0 + c4;
        *reinterpret_cast<ushort4*>(&bhi[o]) = h4;
        *reinterpret_cast<ushort4*>(&blo[o]) = l4;
    }
}

// V^T split (hi only): Vf fp32 [tok][h*64+d] -> VT hi bf16 [bh][d][s(2048)].
__global__ __launch_bounds__(256) void vt_split_kernel(const float* __restrict__ Vf,
                                                       ushort* __restrict__ vthi) {
    __shared__ float tl[64][65];
    const int st = blockIdx.x, bh = blockIdx.y;
    const int b = bh >> 4, h = bh & 15;
    const int i = threadIdx.x >> 2;          // 0..63
    const int c16 = (threadIdx.x & 3) * 16;  // 0,16,32,48
#pragma unroll
    for (int p = 0; p < 4; p++) {
        const float4 v = *reinterpret_cast<const float4*>(
            &Vf[((size_t)(b * Sq + st * 64 + i)) * Dq + h * 64 + c16 + p * 4]);
        tl[i][c16 + p * 4 + 0] = v.x; tl[i][c16 + p * 4 + 1] = v.y;
        tl[i][c16 + p * 4 + 2] = v.z; tl[i][c16 + p * 4 + 3] = v.w;
    }
    __syncthreads();
    const size_t obase = ((size_t)(bh * 64 + i)) * Sq + st * 64 + c16;
#pragma unroll
    for (int p = 0; p < 4; p++) {
        ushort4 h4;
        h4.x = bf16_rne(tl[c16 + p * 4 + 0][i]);
        h4.y = bf16_rne(tl[c16 + p * 4 + 1][i]);
        h4.z = bf16_rne(tl[c16 + p * 4 + 2][i]);
        h4.w = bf16_rne(tl[c16 + p * 4 + 3][i]);
        *reinterpret_cast<ushort4*>(&vthi[obase + p * 4]) = h4;
    }
}

// ---------------------------------------------------------------------------
// MFMA bf16x3 GEMM (audited; unchanged from passing build).
#define LPITCH 40
__global__ __launch_bounds__(256) void gemm_bf16x3(const ushort* __restrict__ Ahi,
                                                   const ushort* __restrict__ Alo,
                                                   const ushort* __restrict__ Bthi,
                                                   const ushort* __restrict__ Btlo,
                                                   float* __restrict__ C,
                                                   int M, int N, int K) {
    __shared__ ushort lAhi[128 * LPITCH];
    __shared__ ushort lAlo[128 * LPITCH];
    __shared__ ushort lBhi[128 * LPITCH];
    __shared__ ushort lBlo[128 * LPITCH];
    const int tid = threadIdx.x;
    const int lane = tid & 63;
    const int wave = tid >> 6;
    const int wr = wave >> 1, wc = wave & 1;
    const int row0 = blockIdx.y * 128, col0 = blockIdx.x * 128;

    const int srow = tid >> 2;
    const int spart = tid & 3;
    const int lrow = lane & 15;
    const int kgrp = lane >> 4;

    f32x4 acc[4][4];
#pragma unroll
    for (int i = 0; i < 4; i++)
#pragma unroll
        for (int j = 0; j < 4; j++) acc[i][j] = (f32x4)(0.f);

    for (int k0 = 0; k0 < K; k0 += 32) {
        const size_t ga0 = (size_t)(row0 + srow) * K + k0 + spart * 8;
        const size_t ga1 = ga0 + (size_t)64 * K;
        const size_t gb0 = (size_t)(col0 + srow) * K + k0 + spart * 8;
        const size_t gb1 = gb0 + (size_t)64 * K;
        const short8v ah0 = *reinterpret_cast<const short8v*>(Ahi + ga0);
        const short8v ah1 = *reinterpret_cast<const short8v*>(Ahi + ga1);
        const short8v al0 = *reinterpret_cast<const short8v*>(Alo + ga0);
        const short8v al1 = *reinterpret_cast<const short8v*>(Alo + ga1);
        const short8v bh0 = *reinterpret_cast<const short8v*>(Bthi + gb0);
        const short8v bh1 = *reinterpret_cast<const short8v*>(Bthi + gb1);
        const short8v bl0 = *reinterpret_cast<const short8v*>(Btlo + gb0);
        const short8v bl1 = *reinterpret_cast<const short8v*>(Btlo + gb1);
        __syncthreads();
        const int s0 = srow * LPITCH + spart * 8;
        const int s1 = (srow + 64) * LPITCH + spart * 8;
        *reinterpret_cast<short8v*>(&lAhi[s0]) = ah0;
        *reinterpret_cast<short8v*>(&lAhi[s1]) = ah1;
        *reinterpret_cast<short8v*>(&lAlo[s0]) = al0;
        *reinterpret_cast<short8v*>(&lAlo[s1]) = al1;
        *reinterpret_cast<short8v*>(&lBhi[s0]) = bh0;
        *reinterpret_cast<short8v*>(&lBhi[s1]) = bh1;
        *reinterpret_cast<short8v*>(&lBlo[s0]) = bl0;
        *reinterpret_cast<short8v*>(&lBlo[s1]) = bl1;
        __syncthreads();
        short8v afh[4], afl[4], bfh[4], bfl[4];
#pragma unroll
        for (int im = 0; im < 4; im++) {
            const int a = (wr * 64 + im * 16 + lrow) * LPITCH + kgrp * 8;
            afh[im] = *reinterpret_cast<const short8v*>(&lAhi[a]);
            afl[im] = *reinterpret_cast<const short8v*>(&lAlo[a]);
        }
#pragma unroll
        for (int in = 0; in < 4; in++) {
            const int bb = (wc * 64 + in * 16 + lrow) * LPITCH + kgrp * 8;
            bfh[in] = *reinterpret_cast<const short8v*>(&lBhi[bb]);
            bfl[in] = *reinterpret_cast<const short8v*>(&lBlo[bb]);
        }
#pragma unroll
        for (int im = 0; im < 4; im++)
#pragma unroll
            for (int in = 0; in < 4; in++) {
                acc[im][in] = __builtin_amdgcn_mfma_f32_16x16x32_bf16(afh[im], bfh[in], acc[im][in], 0, 0, 0);
                acc[im][in] = __builtin_amdgcn_mfma_f32_16x16x32_bf16(afh[im], bfl[in], acc[im][in], 0, 0, 0);
                acc[im][in] = __builtin_amdgcn_mfma_f32_16x16x32_bf16(afl[im], bfh[in], acc[im][in], 0, 0, 0);
            }
    }
#pragma unroll
    for (int im = 0; im < 4; im++) {
        const int orow = row0 + wr * 64 + im * 16 + kgrp * 4;
#pragma unroll
        for (int in = 0; in < 4; in++) {
            const int ocol = col0 + wc * 64 + in * 16 + lrow;
#pragma unroll
            for (int j = 0; j < 4; j++) C[(size_t)(orow + j) * N + ocol] = acc[im][in][j];
        }
    }
}

// ---------------------------------------------------------------------------
// h/Gq/Gv fuse (unchanged).
__global__ __launch_bounds__(256) void fuse_hG_kernel(float* TG,
                                                      const float* __restrict__ cw,
                                                      const float* __restrict__ ewq,
                                                      const float* __restrict__ ewv,
                                                      float* __restrict__ Gq) {
    const int lane = threadIdx.x & 63;
    const int wave = threadIdx.x >> 6;
    const int t = blockIdx.x * 4 + wave;
    float* Trow = TG + (size_t)t * NRq;
    float h = 0.f;
#pragma unroll
    for (int n = 0; n < Nq; n++) h = fmaf(cw[t * Nq + n], Trow[n * 64 + lane], h);
#pragma unroll
    for (int n = 0; n < Nq; n++) Gq[(size_t)t * NRq + n * 64 + lane] = ewq[t * Nq + n] * h;
#pragma unroll
    for (int n = 0; n < Nq; n++) Trow[n * 64 + lane] = ewv[t * Nq + n] * h;
}

// ---------------------------------------------------------------------------
// MFMA attention v3. vs v2 (226us, MfmaUtil 16.5, Occ 20.6, conflicts 0):
//  - V hi-only: PV 16->8 MFMA, stage 8->6 loads, LDS 44544->35840 B
//    => 4 blocks/CU, 1024 blocks = ONE flat tranche (tail eliminated)
//  - T5 setprio(1) around QK and PV MFMA clusters
//  - T13 defer-max (THR=8, wave-uniform __all): skip rescale most tiles
#define APITCH 68
#define PPITCH 76
#define STAGE_ISSUE(kt_, R)                                                          \
    do {                                                                             \
        const size_t ksrc = ((size_t)(b * Sq + (kt_) * 64 + srow)) * Dq + h * 64 + sc16; \
        const size_t vsrc = ((size_t)(bh * 64 + srow)) * Sq + (kt_) * 64 + sc16;     \
        R[0] = *reinterpret_cast<const short8v*>(Qhi + ksrc);                        \
        R[1] = *reinterpret_cast<const short8v*>(Qhi + ksrc + 8);                    \
        R[2] = *reinterpret_cast<const short8v*>(Qlo + ksrc);                        \
        R[3] = *reinterpret_cast<const short8v*>(Qlo + ksrc + 8);                    \
        R[4] = *reinterpret_cast<const short8v*>(VThi + vsrc);                       \
        R[5] = *reinterpret_cast<const short8v*>(VThi + vsrc + 8);                   \
    } while (0)
#define STAGE_WRITE(R)                                        \
    do {                                                      \
        const int d0 = srow * APITCH + sc16;                  \
        *reinterpret_cast<short8v*>(&Kh[d0])     = R[0];      \
        *reinterpret_cast<short8v*>(&Kh[d0 + 8]) = R[1];      \
        *reinterpret_cast<short8v*>(&Kl[d0])     = R[2];      \
        *reinterpret_cast<short8v*>(&Kl[d0 + 8]) = R[3];      \
        *reinterpret_cast<short8v*>(&Vh[d0])     = R[4];      \
        *reinterpret_cast<short8v*>(&Vh[d0 + 8]) = R[5];      \
    } while (0)

__global__ __launch_bounds__(256) void attn_mfma_kernel(const ushort* __restrict__ Qhi,
                                                        const ushort* __restrict__ Qlo,
                                                        const ushort* __restrict__ VThi,
                                                        ushort* __restrict__ AOhi,
                                                        ushort* __restrict__ AOlo) {
    __shared__ ushort Kh[64 * APITCH], Kl[64 * APITCH];   // [key][d]
    __shared__ ushort Vh[64 * APITCH];                    // [d][key] (V^T tile, hi only)
    __shared__ ushort Ph[4][16 * PPITCH];                 // per-wave P (hi only)
    const int tid = threadIdx.x;
    const int lane = tid & 63, w = tid >> 6;
    const int lr = lane & 15, lg = lane >> 4;
    const int bh = blockIdx.y;
    const int b = bh >> 4, h = bh & 15;
    const int srow = tid >> 2;           // staging row 0..63
    const int sc16 = (tid & 3) * 16;     // staging col (ushorts)

#pragma unroll 1
    for (int pass = 0; pass < 2; pass++) {
        const int qt = pass ? 31 - blockIdx.x : blockIdx.x;
        // Q A-frags (pre-scaled by sqrt(1/8)); held in regs for the whole pass
        const size_t qbase = ((size_t)(b * Sq + qt * 64 + w * 16 + lr)) * Dq + h * 64 + lg * 8;
        const short8v aqh0 = *reinterpret_cast<const short8v*>(Qhi + qbase);
        const short8v aqh1 = *reinterpret_cast<const short8v*>(Qhi + qbase + 32);
        const short8v aql0 = *reinterpret_cast<const short8v*>(Qlo + qbase);
        const short8v aql1 = *reinterpret_cast<const short8v*>(Qlo + qbase + 32);

        float m[4] = {-1e30f, -1e30f, -1e30f, -1e30f};
        float l[4] = {0.f, 0.f, 0.f, 0.f};
        f32x4 out[4];
#pragma unroll
        for (int dt = 0; dt < 4; dt++) out[dt] = (f32x4)(0.f);

        // prologue: stage kt=0
        {
            short8v R[6];
            STAGE_ISSUE(0, R);
            __syncthreads();  // prev pass readers done before overwrite
            STAGE_WRITE(R);
        }
        __syncthreads();

        for (int kt = 0; kt <= qt; kt++) {
            const bool more = kt < qt;
            short8v NX[6];
            if (more) STAGE_ISSUE(kt + 1, NX);  // T14: issue early, write late

            // ---- QK^T: S[16 q-rows][64 keys] ----
            f32x4 s[4];
#pragma unroll
            for (int ct = 0; ct < 4; ct++) s[ct] = (f32x4)(0.f);
            __builtin_amdgcn_s_setprio(1);
#pragma unroll
            for (int ct = 0; ct < 4; ct++) {
                {
                    const int ka = (ct * 16 + lr) * APITCH + lg * 8;
                    const short8v bkh = *reinterpret_cast<const short8v*>(&Kh[ka]);
                    const short8v bkl = *reinterpret_cast<const short8v*>(&Kl[ka]);
                    s[ct] = __builtin_amdgcn_mfma_f32_16x16x32_bf16(aqh0, bkh, s[ct], 0, 0, 0);
                    s[ct] = __builtin_amdgcn_mfma_f32_16x16x32_bf16(aqh0, bkl, s[ct], 0, 0, 0);
                    s[ct] = __builtin_amdgcn_mfma_f32_16x16x32_bf16(aql0, bkh, s[ct], 0, 0, 0);
                }
                {
                    const int ka = (ct * 16 + lr) * APITCH + 32 + lg * 8;
                    const short8v bkh = *reinterpret_cast<const short8v*>(&Kh[ka]);
                    const short8v bkl = *reinterpret_cast<const short8v*>(&Kl[ka]);
                    s[ct] = __builtin_amdgcn_mfma_f32_16x16x32_bf16(aqh1, bkh, s[ct], 0, 0, 0);
                    s[ct] = __builtin_amdgcn_mfma_f32_16x16x32_bf16(aqh1, bkl, s[ct], 0, 0, 0);
                    s[ct] = __builtin_amdgcn_mfma_f32_16x16x32_bf16(aql1, bkh, s[ct], 0, 0, 0);
                }
            }
            __builtin_amdgcn_s_setprio(0);
            if (kt == qt) {  // causal mask on diagonal tile only
#pragma unroll
                for (int ct = 0; ct < 4; ct++)
#pragma unroll
                    for (int j = 0; j < 4; j++)
                        if ((ct * 16 + lr) > (w * 16 + lg * 4 + j)) s[ct][j] = -1e30f;
            }
            // ---- online softmax with defer-max (wave-uniform branch) ----
            float pm[4];
#pragma unroll
            for (int j = 0; j < 4; j++) {
                float t = fmaxf(fmaxf(s[0][j], s[1][j]), fmaxf(s[2][j], s[3][j]));
                t = fmaxf(t, __shfl_xor(t, 1));
                t = fmaxf(t, __shfl_xor(t, 2));
                t = fmaxf(t, __shfl_xor(t, 4));
                t = fmaxf(t, __shfl_xor(t, 8));
                pm[j] = t;
            }
            int ok = (pm[0] <= m[0] + 8.f) & (pm[1] <= m[1] + 8.f) &
                     (pm[2] <= m[2] + 8.f) & (pm[3] <= m[3] + 8.f);
            if (!__all(ok)) {  // rescale path (rare after first tiles)
#pragma unroll
                for (int j = 0; j < 4; j++) {
                    const float mn = fmaxf(m[j], pm[j]);
                    const float c = __expf(m[j] - mn);
                    m[j] = mn;
                    l[j] *= c;
#pragma unroll
                    for (int dt = 0; dt < 4; dt++) out[dt][j] *= c;
                }
            }
            float rs[4] = {0.f, 0.f, 0.f, 0.f};
#pragma unroll
            for (int ct = 0; ct < 4; ct++)
#pragma unroll
                for (int j = 0; j < 4; j++) {
                    const float p = __expf(s[ct][j] - m[j]);
                    rs[j] += p;
                    Ph[w][(lg * 4 + j) * PPITCH + ct * 16 + lr] = bf16_rne(p);
                }
#pragma unroll
            for (int j = 0; j < 4; j++) {
                float t = rs[j];
                t += __shfl_xor(t, 1);
                t += __shfl_xor(t, 2);
                t += __shfl_xor(t, 4);
                t += __shfl_xor(t, 8);
                l[j] += t;
            }
            // ---- PV (P hi, V hi; wave-private P LDS, same-wave ordering) ----
            __builtin_amdgcn_s_setprio(1);
#pragma unroll
            for (int kp = 0; kp < 2; kp++) {
                const short8v pah = *reinterpret_cast<const short8v*>(
                    &Ph[w][lr * PPITCH + kp * 32 + lg * 8]);
#pragma unroll
                for (int dt = 0; dt < 4; dt++) {
                    const int va = (dt * 16 + lr) * APITCH + kp * 32 + lg * 8;
                    const short8v bvh = *reinterpret_cast<const short8v*>(&Vh[va]);
                    out[dt] = __builtin_amdgcn_mfma_f32_16x16x32_bf16(pah, bvh, out[dt], 0, 0, 0);
                }
            }
            __builtin_amdgcn_s_setprio(0);
            __syncthreads();             // all waves done reading K/V LDS
            if (more) STAGE_WRITE(NX);   // write next tile
            __syncthreads();
        }
        // ---- epilogue: normalize + split-write bf16 hi/lo for GEMM4 ----
#pragma unroll
        for (int j = 0; j < 4; j++) l[j] = 1.f / l[j];
#pragma unroll
        for (int dt = 0; dt < 4; dt++)
#pragma unroll
            for (int j = 0; j < 4; j++) {
                const float v = out[dt][j] * l[j];
                ushort vh, vl;
                split2(v, vh, vl);
                const size_t o = ((size_t)(b * Sq + qt * 64 + w * 16 + lg * 4 + j)) * Dq
                                 + h * 64 + dt * 16 + lr;
                AOhi[o] = vh;
                AOlo[o] = vl;
            }
    }
}

// ---------------------------------------------------------------------------
extern "C" void kernel_launch(void* const* d_in, const int* in_sizes, int n_in,
                              void* d_out, int out_size, void* d_ws, size_t ws_size,
                              hipStream_t stream) {
    (void)in_sizes; (void)n_in; (void)out_size; (void)ws_size;
    const float* x   = (const float*)d_in[0];
    const float* cw  = (const float*)d_in[1];
    const float* ewq = (const float*)d_in[2];
    const float* ewv = (const float*)d_in[3];
    const float* cn  = (const float*)d_in[4];
    const float* enq = (const float*)d_in[5];
    const float* env = (const float*)d_in[6];
    const float* wo  = (const float*)d_in[7];
    float* out = (float*)d_out;
    float* ws  = (float*)d_ws;

    // Workspace 112 MB, phase-based reuse (identical to passing plan).
    const size_t MEG = 1024 * 1024;
    float* Tg  = ws;
    float* GqQ = ws + 8 * MEG;
    float* Vf  = out;                    // V fp32 in d_out (dead until GEMM4)
    ushort* us = (ushort*)(ws + 16 * MEG);
    ushort* SAhi = us;
    ushort* SAlo = us + 8 * MEG;
    ushort* cBhi = us + 16 * MEG;
    ushort* cBlo = us + 17 * MEG;
    ushort* eqBhi = us + 18 * MEG;
    ushort* eqBlo = us + 19 * MEG;
    ushort* evBhi = us + 20 * MEG;
    ushort* evBlo = us + 21 * MEG;
    ushort* woBhi = us + 22 * MEG;
    ushort* woBlo = us + 23 * MEG;
    ushort* QShi = (ushort*)Tg;          // after Tg fp32 dead
    ushort* QSlo = QShi + 8 * MEG;
    ushort* VThi = (ushort*)GqQ;         // after GqQ fp32 dead

    split_kernel<<<8192, 256, 0, stream>>>(x, SAhi, SAlo, 1.0f);
    callT_split_kernel<<<4096, 256, 0, stream>>>(cn, cBhi, cBlo);
    transpose_split_kernel<<<256, 256, 0, stream>>>(enq, eqBhi, eqBlo);
    transpose_split_kernel<<<256, 256, 0, stream>>>(env, evBhi, evBlo);
    split_kernel<<<1024, 256, 0, stream>>>(wo, woBhi, woBlo, 1.0f);

    const dim3 gg(8, 64);
    gemm_bf16x3<<<gg, 256, 0, stream>>>(SAhi, SAlo, cBhi, cBlo, Tg, Mq, NRq, Dq);    // T = X@C_all
    fuse_hG_kernel<<<2048, 256, 0, stream>>>(Tg, cw, ewq, ewv, GqQ);                 // h, Gq; Gv over T
    split_kernel<<<8192, 256, 0, stream>>>(Tg, SAhi, SAlo, 1.0f);                    // Gv split
    gemm_bf16x3<<<gg, 256, 0, stream>>>(SAhi, SAlo, evBhi, evBlo, Vf, Mq, Dq, NRq);  // V = Gv@Ev
    split_kernel<<<8192, 256, 0, stream>>>(GqQ, SAhi, SAlo, 1.0f);                   // Gq split
    gemm_bf16x3<<<gg, 256, 0, stream>>>(SAhi, SAlo, eqBhi, eqBlo, GqQ, Mq, Dq, NRq); // Q = Gq@Eqk
    // Q split pre-scaled by sqrt(1/8): Q==K so the QK product carries 1/8.
    split_kernel<<<8192, 256, 0, stream>>>(GqQ, QShi, QSlo, 0.35355339f);
    vt_split_kernel<<<dim3(32, 64), 256, 0, stream>>>(Vf, VThi);
    attn_mfma_kernel<<<dim3(16, 64), 256, 0, stream>>>(QShi, QSlo, VThi,
                                                       SAhi, SAlo);                  // attn -> SA bf16
    gemm_bf16x3<<<gg, 256, 0, stream>>>(SAhi, SAlo, woBhi, woBlo, out, Mq, Dq, Dq);  // Y = attn@W_O^T
}